// Round 13
// baseline (71.307 us; speedup 1.0000x reference)
//
#include <hip/hip_runtime.h>
#include <hip/hip_bf16.h>
#include <cstring>

// Species-routed per-atom 3-layer MLP via MFMA, round 13.
// = R11 (best: 65.4us) with ONE lever: LDS cut to exactly 32KB so 5 blocks/CU
// fit (5 x 32768 = 163840 = 160KB exactly), raising the occupancy cap from
// 16 to 20 waves/CU. Changes vs R11:
//   - XSTR 72 -> 64 (row = exactly 64 shorts; koff max 56+8 fits, no pad)
//   - stride-64 would be 16-way bank-conflicted (128B rows) -> XOR swizzle
//     on 8B chunks: c' = c ^ ((row&7)<<1). Even key keeps b128 reads on two
//     contiguous chunks; bijective per row; same involution on write+read.
//   - Ob aliased into each wave's own Hb quarter (written only after that
//     region's last read, wave-private) -> no extra LDS.
//   - __launch_bounds__(256, 5).
// R12's aligned-window loads REVERTED (regressed: RA refused the pressure).

#define NN    4096
#define AA    256
#define DIN   39
#define HH    50
#define ATILE 4
#define NTILE 64
#define XSTR  64                   // H1 LDS row stride (shorts): 128 B
#define WFS   (2 * 2 * 4 * 64 * 8) // shorts per species, frag layout (16 KB)

typedef __attribute__((ext_vector_type(8))) short bf16x8;
typedef __attribute__((ext_vector_type(4))) float f32x4;
typedef float f32x4u __attribute__((ext_vector_type(4), aligned(4)));

__device__ __forceinline__ float fast_silu(float x) {
    return x * __builtin_amdgcn_rcpf(1.0f + __expf(-x));
}
__device__ __forceinline__ unsigned pack_bf2(float a, float b) {
    __hip_bfloat162 h = __float22bfloat162_rn(float2{a, b});
    unsigned u; memcpy(&u, &h, 4); return u;
}
__device__ __forceinline__ bf16x8 cvt8(f32x4u a, f32x4u b) {
    unsigned u[4];
    u[0] = pack_bf2(a[0], a[1]);
    u[1] = pack_bf2(a[2], a[3]);
    u[2] = pack_bf2(b[0], b[1]);
    u[3] = pack_bf2(b[2], b[3]);
    bf16x8 r; memcpy(&r, u, 16); return r;
}

// ---------------- prep: weights -> per-lane frag layout (unchanged) --------
__global__ __launch_bounds__(256) void prep_weights(
    const float* __restrict__ W1, const float* __restrict__ b1,
    const float* __restrict__ W2, const float* __restrict__ b2,
    const float* __restrict__ W3, const float* __restrict__ b3,
    unsigned short* __restrict__ Wf, float* __restrict__ Bp)
{
    const int s = blockIdx.x >> 3;
    const int c = blockIdx.x & 7;
    const int t = threadIdx.x;
    const float* __restrict__ w1g = W1 + s * (DIN * HH);
    const float* __restrict__ w2g = W2 + s * (HH * HH);
    unsigned* __restrict__ outw = (unsigned*)(Wf + (size_t)s * WFS);

    #pragma unroll
    for (int i = 0; i < 2; ++i) {
        const int d    = c * 512 + i * 256 + t;
        const int j2   = d & 3;
        const int lane = (d >> 2) & 63;
        const int mt   = (d >> 8) & 3;
        const int ks   = (d >> 10) & 1;
        const int L    = (d >> 11) & 1;
        const int col  = 16 * mt + (lane & 15);
        const int k0   = ks * 32 + 8 * (lane >> 4) + 2 * j2;
        const int k1   = k0 + 1;
        float v0 = 0.f, v1 = 0.f;
        if (col < HH) {
            if (L == 0) {
                if (k0 < DIN) v0 = w1g[k0 * HH + col];
                if (k1 < DIN) v1 = w1g[k1 * HH + col];
            } else {
                if (k0 < HH)  v0 = w2g[k0 * HH + col];
                if (k1 < HH)  v1 = w2g[k1 * HH + col];
            }
        }
        outw[d] = pack_bf2(v0, v1);
    }
    if (c == 0 && t < 64) {
        float* bp = Bp + s * 256;
        const bool v = t < HH;
        bp[t]       = v ? b1[s * HH + t] : 0.0f;
        bp[64 + t]  = v ? b2[s * HH + t] : 0.0f;
        bp[128 + t] = v ? W3[s * HH + t] : 0.0f;
        bp[192 + t] = b3[s];
    }
}

// ---------------- main kernel ----------------
__global__ __launch_bounds__(256, 5) void atomic_mlp_mfma(
    const float* __restrict__ desc,
    const int*   __restrict__ numbers,
    const unsigned short* __restrict__ Wf,
    const float* __restrict__ Bp,
    float*       __restrict__ out)
{
    // H1 for 4 atoms x 64 rows, stride 64 shorts, XOR-swizzled. 32768 B total.
    // Each wave's output floats alias the head of its own quarter (see below).
    __shared__ unsigned short Hb[ATILE * NTILE * XSTR];

    const int a0 = blockIdx.x * ATILE;
    const int n0 = blockIdx.y * NTILE;
    const int t  = threadIdx.x;
    const int lane = t & 63;
    const int lg   = lane >> 4;
    const int lr   = lane & 15;
    const int wid  = t >> 6;
    const int wbase = wid * NTILE;      // this wave's H1 row base (its atom)

    // wave-uniform species -> SGPR
    const int sw = __builtin_amdgcn_readfirstlane(numbers[a0 + wid]);
    const unsigned short* __restrict__ wfs = Wf + (size_t)sw * WFS;
    const float* __restrict__ bp = Bp + sw * 256;

    // ---- phase-1 working set: W1 A-frags + b1 (pinned into registers) ----
    bf16x8 w1f[2][4];
    #pragma unroll
    for (int ks = 0; ks < 2; ++ks)
        #pragma unroll
        for (int mt = 0; mt < 4; ++mt)
            w1f[ks][mt] = *(const bf16x8*)&wfs[((ks * 4 + mt) * 64 + lane) * 8];
    f32x4 b1q[4];
    #pragma unroll
    for (int mt = 0; mt < 4; ++mt)
        b1q[mt] = *(const f32x4*)&bp[16 * mt + 4 * lg];
    #pragma unroll
    for (int ks = 0; ks < 2; ++ks)
        #pragma unroll
        for (int mt = 0; mt < 4; ++mt)
            asm volatile("" : "+v"(w1f[ks][mt]));
    #pragma unroll
    for (int mt = 0; mt < 4; ++mt) asm volatile("" : "+v"(b1q[mt]));

    const float bias3 = bp[192];

    // ---- Layer 1: X B-frags straight from global (as R11, proven) ----
    //   xf0: k=8lg..8lg+7 (always in-bounds, max idx rbase+31)
    //   xf1: lg=0 -> k=32..38 valid; lg>0 don't-care (zero weights).
    //        xc = load(rbase+32); xd = load(rbase+35) rotated {y,z,w,x}.
    // C^T: lane holds H1[row][16mt+4lg+r] -> one swizzled b64 write per tile;
    // cols 50..63 get silu(0+0)=0, so every chunk of the row is initialized.
    const size_t arow = (size_t)(a0 + wid) * DIN;
    #pragma unroll
    for (int nt = 0; nt < 4; ++nt) {
        const size_t rbase = (size_t)(n0 + 16 * nt + lr) * (AA * DIN) + arow;
        const f32x4u xa = *(const f32x4u*)(desc + rbase + 8 * lg);
        const f32x4u xb = *(const f32x4u*)(desc + rbase + 8 * lg + 4);
        const f32x4u xc = *(const f32x4u*)(desc + rbase + 32);
        const f32x4u xv = *(const f32x4u*)(desc + rbase + 35);
        f32x4u xd;
        xd[0] = xv[1]; xd[1] = xv[2]; xd[2] = xv[3]; xd[3] = xv[0];
        const bf16x8 xf0 = cvt8(xa, xb);
        const bf16x8 xf1 = cvt8(xc, xd);
        const int row = wbase + 16 * nt + lr;
        const int swk = (row & 7) << 1;              // even XOR key, 8B chunks
        #pragma unroll
        for (int mt = 0; mt < 4; ++mt) {
            f32x4 c = f32x4{0.f, 0.f, 0.f, 0.f};
            c = __builtin_amdgcn_mfma_f32_16x16x32_bf16(w1f[0][mt], xf0, c, 0, 0, 0);
            c = __builtin_amdgcn_mfma_f32_16x16x32_bf16(w1f[1][mt], xf1, c, 0, 0, 0);
            const unsigned u0 = pack_bf2(fast_silu(c[0] + b1q[mt][0]),
                                         fast_silu(c[1] + b1q[mt][1]));
            const unsigned u1 = pack_bf2(fast_silu(c[2] + b1q[mt][2]),
                                         fast_silu(c[3] + b1q[mt][3]));
            uint2 uu; uu.x = u0; uu.y = u1;
            const int ch = (4 * mt + lg) ^ swk;      // swizzled 8B chunk
            *(uint2*)&Hb[row * XSTR + ch * 4] = uu;
        }
    }

    // ---- phase-2 working set: W2 A-frags + b2 + w3 (pinned) ----
    bf16x8 w2f[2][4];
    #pragma unroll
    for (int ks = 0; ks < 2; ++ks)
        #pragma unroll
        for (int mt = 0; mt < 4; ++mt)
            w2f[ks][mt] = *(const bf16x8*)&wfs[((8 + ks * 4 + mt) * 64 + lane) * 8];
    f32x4 b2q[4], w3q[4];
    #pragma unroll
    for (int mt = 0; mt < 4; ++mt) {
        b2q[mt] = *(const f32x4*)&bp[64 + 16 * mt + 4 * lg];
        w3q[mt] = *(const f32x4*)&bp[128 + 16 * mt + 4 * lg];
    }
    #pragma unroll
    for (int ks = 0; ks < 2; ++ks)
        #pragma unroll
        for (int mt = 0; mt < 4; ++mt)
            asm volatile("" : "+v"(w2f[ks][mt]));
    #pragma unroll
    for (int mt = 0; mt < 4; ++mt) {
        asm volatile("" : "+v"(b2q[mt]));
        asm volatile("" : "+v"(w3q[mt]));
    }

    // Wave-private output region: aliases the head of this wave's Hb quarter.
    // Safe: Ob floats 16nt..16nt+15 (bytes 0..255 = rows 0..1 of the quarter)
    // are written at the END of iteration nt, strictly after nt=0's reads of
    // rows 0..15 (wave-lockstep, in-order LDS ops); no other wave touches it.
    float* __restrict__ ObW = (float*)&Hb[wbase * XSTR];

    // ---- Layer 2 + 3: H1 frags from LDS (wave-private, no barrier) ----
    #pragma unroll
    for (int nt = 0; nt < 4; ++nt) {
        const int row = wbase + 16 * nt + lr;
        const int swk = (row & 7) << 1;
        const int c0 = (2 * lg) ^ swk;               // ks=0 chunk pair base
        const int c1 = (8 + 2 * lg) ^ swk;           // ks=1 chunk pair base
        const bf16x8 hf0 = *(const bf16x8*)&Hb[row * XSTR + c0 * 4];
        const bf16x8 hf1 = *(const bf16x8*)&Hb[row * XSTR + c1 * 4];
        float p = 0.f;
        #pragma unroll
        for (int mt = 0; mt < 4; ++mt) {
            f32x4 c = f32x4{0.f, 0.f, 0.f, 0.f};
            c = __builtin_amdgcn_mfma_f32_16x16x32_bf16(w2f[0][mt], hf0, c, 0, 0, 0);
            c = __builtin_amdgcn_mfma_f32_16x16x32_bf16(w2f[1][mt], hf1, c, 0, 0, 0);
            p += fast_silu(c[0] + b2q[mt][0]) * w3q[mt][0];
            p += fast_silu(c[1] + b2q[mt][1]) * w3q[mt][1];
            p += fast_silu(c[2] + b2q[mt][2]) * w3q[mt][2];
            p += fast_silu(c[3] + b2q[mt][3]) * w3q[mt][3];
        }
        p += __shfl_xor(p, 16);             // reduce across the 4 lg groups
        p += __shfl_xor(p, 32);
        if (lg == 0) ObW[16 * nt + lr] = p + bias3;
    }

    __syncthreads();   // all waves' ObW regions complete

    // ---- cooperative out store: one float4 wave-store covers the block ----
    if (t < NTILE) {
        float4 o;
        o.x = ((const float*)&Hb[0 * NTILE * XSTR])[t];
        o.y = ((const float*)&Hb[1 * NTILE * XSTR])[t];
        o.z = ((const float*)&Hb[2 * NTILE * XSTR])[t];
        o.w = ((const float*)&Hb[3 * NTILE * XSTR])[t];
        *(float4*)&out[(size_t)(n0 + t) * AA + a0] = o;
    }
}

extern "C" void kernel_launch(void* const* d_in, const int* in_sizes, int n_in,
                              void* d_out, int out_size, void* d_ws, size_t ws_size,
                              hipStream_t stream) {
    const float* desc    = (const float*)d_in[0];
    const int*   numbers = (const int*)  d_in[1];
    const float* W1      = (const float*)d_in[2];
    const float* b1      = (const float*)d_in[3];
    const float* W2      = (const float*)d_in[4];
    const float* b2      = (const float*)d_in[5];
    const float* W3      = (const float*)d_in[6];
    const float* b3      = (const float*)d_in[7];
    float*       out     = (float*)d_out;

    unsigned short* Wf = (unsigned short*)d_ws;                  // 8*16384 B
    float*          Bp = (float*)((char*)d_ws + 8 * WFS * 2);    // 8*256 f32

    hipLaunchKernelGGL(prep_weights, dim3(64), dim3(256), 0, stream,
                       W1, b1, W2, b2, W3, b3, Wf, Bp);

    dim3 grid(AA / ATILE, NN / NTILE);
    hipLaunchKernelGGL(atomic_mlp_mfma, grid, dim3(256), 0, stream,
                       desc, numbers, Wf, Bp, out);
}

// Round 14
// 61.100 us; speedup vs baseline: 1.1671x; 1.1671x over previous
//
#include <hip/hip_runtime.h>
#include <hip/hip_bf16.h>
#include <cstring>

// Species-routed per-atom 3-layer MLP via MFMA, round 14.
// = R11 (best passing: 65.4us) + two exact-math VALU cuts:
//  (1) bias-as-C-init: accumulator slot c[r] is exactly col 16mt+4lg+r =
//      b1q[mt][r] / b2q[mt][r], so init c = bias quad instead of 0-init +
//      4 v_add afterwards (MFMA adds into C for free). -128 VALU/lane.
//  (2) mt=3 static skips: cols >=50 only ever multiply prep-zeroed weight
//      rows, so L1 writes constant 0 for the u1 half (skip 2 silu + pack)
//      and L2 skips the i=2,3 terms (w3q[3][2..3]==0 for every lane).
// R12 (aligned windows) and R13 (32KB swizzle) both REVERTED — both
// regressed; achieved occupancy is pinned at ~38% regardless of static cap.

#define NN    4096
#define AA    256
#define DIN   39
#define HH    50
#define ATILE 4
#define NTILE 64
#define XSTR  72                   // H1 LDS row stride (shorts): 144 B
#define WFS   (2 * 2 * 4 * 64 * 8) // shorts per species, frag layout (16 KB)

typedef __attribute__((ext_vector_type(8))) short bf16x8;
typedef __attribute__((ext_vector_type(4))) float f32x4;
typedef float f32x4u __attribute__((ext_vector_type(4), aligned(4)));

__device__ __forceinline__ float fast_silu(float x) {
    return x * __builtin_amdgcn_rcpf(1.0f + __expf(-x));
}
__device__ __forceinline__ unsigned pack_bf2(float a, float b) {
    __hip_bfloat162 h = __float22bfloat162_rn(float2{a, b});
    unsigned u; memcpy(&u, &h, 4); return u;
}
__device__ __forceinline__ bf16x8 cvt8(f32x4u a, f32x4u b) {
    unsigned u[4];
    u[0] = pack_bf2(a[0], a[1]);
    u[1] = pack_bf2(a[2], a[3]);
    u[2] = pack_bf2(b[0], b[1]);
    u[3] = pack_bf2(b[2], b[3]);
    bf16x8 r; memcpy(&r, u, 16); return r;
}

// ---------------- prep: weights -> per-lane frag layout (unchanged) --------
// Wf[s] dword d = [L][ks][mt][lane][j2]: wcol=16*mt+(lane&15),
// k=ks*32+8*(lane>>4)+2*j2(+1); zero outside valid ranges.
// Bp[s][0..3][64] f32 = b1, b2, w3, b3(broadcast), zero-padded.
__global__ __launch_bounds__(256) void prep_weights(
    const float* __restrict__ W1, const float* __restrict__ b1,
    const float* __restrict__ W2, const float* __restrict__ b2,
    const float* __restrict__ W3, const float* __restrict__ b3,
    unsigned short* __restrict__ Wf, float* __restrict__ Bp)
{
    const int s = blockIdx.x >> 3;
    const int c = blockIdx.x & 7;
    const int t = threadIdx.x;
    const float* __restrict__ w1g = W1 + s * (DIN * HH);
    const float* __restrict__ w2g = W2 + s * (HH * HH);
    unsigned* __restrict__ outw = (unsigned*)(Wf + (size_t)s * WFS);

    #pragma unroll
    for (int i = 0; i < 2; ++i) {
        const int d    = c * 512 + i * 256 + t;
        const int j2   = d & 3;
        const int lane = (d >> 2) & 63;
        const int mt   = (d >> 8) & 3;
        const int ks   = (d >> 10) & 1;
        const int L    = (d >> 11) & 1;
        const int col  = 16 * mt + (lane & 15);
        const int k0   = ks * 32 + 8 * (lane >> 4) + 2 * j2;
        const int k1   = k0 + 1;
        float v0 = 0.f, v1 = 0.f;
        if (col < HH) {
            if (L == 0) {
                if (k0 < DIN) v0 = w1g[k0 * HH + col];
                if (k1 < DIN) v1 = w1g[k1 * HH + col];
            } else {
                if (k0 < HH)  v0 = w2g[k0 * HH + col];
                if (k1 < HH)  v1 = w2g[k1 * HH + col];
            }
        }
        outw[d] = pack_bf2(v0, v1);
    }
    if (c == 0 && t < 64) {
        float* bp = Bp + s * 256;
        const bool v = t < HH;
        bp[t]       = v ? b1[s * HH + t] : 0.0f;
        bp[64 + t]  = v ? b2[s * HH + t] : 0.0f;
        bp[128 + t] = v ? W3[s * HH + t] : 0.0f;
        bp[192 + t] = b3[s];
    }
}

// ---------------- main kernel ----------------
__global__ __launch_bounds__(256, 4) void atomic_mlp_mfma(
    const float* __restrict__ desc,
    const int*   __restrict__ numbers,
    const unsigned short* __restrict__ Wf,
    const float* __restrict__ Bp,
    float*       __restrict__ out)
{
    __shared__ unsigned short Hb[ATILE * NTILE * XSTR];   // H1 only (36 KB)
    __shared__ float          Ob[ATILE * NTILE];          // outputs (1 KB)

    const int a0 = blockIdx.x * ATILE;
    const int n0 = blockIdx.y * NTILE;
    const int t  = threadIdx.x;
    const int lane = t & 63;
    const int lg   = lane >> 4;
    const int lr   = lane & 15;
    const int wid  = t >> 6;
    const int wbase = wid * NTILE;      // this wave's H1 row base (its atom)

    // wave-uniform species -> SGPR
    const int sw = __builtin_amdgcn_readfirstlane(numbers[a0 + wid]);
    const unsigned short* __restrict__ wfs = Wf + (size_t)sw * WFS;
    const float* __restrict__ bp = Bp + sw * 256;

    // ---- phase-1 working set: W1 A-frags + b1 (pinned into registers) ----
    bf16x8 w1f[2][4];
    #pragma unroll
    for (int ks = 0; ks < 2; ++ks)
        #pragma unroll
        for (int mt = 0; mt < 4; ++mt)
            w1f[ks][mt] = *(const bf16x8*)&wfs[((ks * 4 + mt) * 64 + lane) * 8];
    f32x4 b1q[4];
    #pragma unroll
    for (int mt = 0; mt < 4; ++mt)
        b1q[mt] = *(const f32x4*)&bp[16 * mt + 4 * lg];
    #pragma unroll
    for (int ks = 0; ks < 2; ++ks)
        #pragma unroll
        for (int mt = 0; mt < 4; ++mt)
            asm volatile("" : "+v"(w1f[ks][mt]));
    #pragma unroll
    for (int mt = 0; mt < 4; ++mt) asm volatile("" : "+v"(b1q[mt]));

    const float bias3 = bp[192];

    // ---- Layer 1: X B-frags straight from global (as R11, proven) ----
    //   xf0: k=8lg..8lg+7 (always in-bounds, max idx rbase+31)
    //   xf1: lg=0 -> k=32..38 valid; lg>0 don't-care (zero weights).
    //        xc = load(rbase+32); xd = load(rbase+35) rotated {y,z,w,x}.
    // C^T: lane holds H1[row][16mt+4lg+r]; accumulator INITIALIZED with the
    // bias quad (exact col match) -> no post-add. mt=3: u1 half (cols >=50
    // for every lg) only meets zero W2 rows -> constant 0, silu skipped.
    const size_t arow = (size_t)(a0 + wid) * DIN;
    #pragma unroll
    for (int nt = 0; nt < 4; ++nt) {
        const size_t rbase = (size_t)(n0 + 16 * nt + lr) * (AA * DIN) + arow;
        const f32x4u xa = *(const f32x4u*)(desc + rbase + 8 * lg);
        const f32x4u xb = *(const f32x4u*)(desc + rbase + 8 * lg + 4);
        const f32x4u xc = *(const f32x4u*)(desc + rbase + 32);
        const f32x4u xv = *(const f32x4u*)(desc + rbase + 35);
        f32x4u xd;
        xd[0] = xv[1]; xd[1] = xv[2]; xd[2] = xv[3]; xd[3] = xv[0];
        const bf16x8 xf0 = cvt8(xa, xb);
        const bf16x8 xf1 = cvt8(xc, xd);
        #pragma unroll
        for (int mt = 0; mt < 4; ++mt) {
            f32x4 c = b1q[mt];                       // bias as C-init
            c = __builtin_amdgcn_mfma_f32_16x16x32_bf16(w1f[0][mt], xf0, c, 0, 0, 0);
            c = __builtin_amdgcn_mfma_f32_16x16x32_bf16(w1f[1][mt], xf1, c, 0, 0, 0);
            const unsigned u0 = pack_bf2(fast_silu(c[0]), fast_silu(c[1]));
            unsigned u1;
            if (mt == 3) u1 = 0u;                    // cols >=50: zero-W2 rows
            else         u1 = pack_bf2(fast_silu(c[2]), fast_silu(c[3]));
            uint2 uu; uu.x = u0; uu.y = u1;
            *(uint2*)&Hb[(wbase + 16 * nt + lr) * XSTR + 16 * mt + 4 * lg] = uu;
        }
    }

    // ---- phase-2 working set: W2 A-frags + b2 + w3 (pinned) ----
    bf16x8 w2f[2][4];
    #pragma unroll
    for (int ks = 0; ks < 2; ++ks)
        #pragma unroll
        for (int mt = 0; mt < 4; ++mt)
            w2f[ks][mt] = *(const bf16x8*)&wfs[((8 + ks * 4 + mt) * 64 + lane) * 8];
    f32x4 b2q[4], w3q[4];
    #pragma unroll
    for (int mt = 0; mt < 4; ++mt) {
        b2q[mt] = *(const f32x4*)&bp[64 + 16 * mt + 4 * lg];
        w3q[mt] = *(const f32x4*)&bp[128 + 16 * mt + 4 * lg];
    }
    #pragma unroll
    for (int ks = 0; ks < 2; ++ks)
        #pragma unroll
        for (int mt = 0; mt < 4; ++mt)
            asm volatile("" : "+v"(w2f[ks][mt]));
    #pragma unroll
    for (int mt = 0; mt < 4; ++mt) {
        asm volatile("" : "+v"(b2q[mt]));
        asm volatile("" : "+v"(w3q[mt]));
    }

    // ---- Layer 2 + 3: H1 frags from LDS (wave-private, no barrier) ----
    // mt=3: i=2,3 terms have w3q==0 for EVERY lane (cols >=50) -> skipped.
    #pragma unroll
    for (int nt = 0; nt < 4; ++nt) {
        const int row = wbase + 16 * nt + lr;
        const bf16x8 hf0 = *(const bf16x8*)&Hb[row * XSTR + 8 * lg];
        const bf16x8 hf1 = *(const bf16x8*)&Hb[row * XSTR + 32 + 8 * lg];
        float p = 0.f;
        #pragma unroll
        for (int mt = 0; mt < 4; ++mt) {
            f32x4 c = b2q[mt];                       // bias as C-init
            c = __builtin_amdgcn_mfma_f32_16x16x32_bf16(w2f[0][mt], hf0, c, 0, 0, 0);
            c = __builtin_amdgcn_mfma_f32_16x16x32_bf16(w2f[1][mt], hf1, c, 0, 0, 0);
            p += fast_silu(c[0]) * w3q[mt][0];
            p += fast_silu(c[1]) * w3q[mt][1];
            if (mt < 3) {
                p += fast_silu(c[2]) * w3q[mt][2];
                p += fast_silu(c[3]) * w3q[mt][3];
            }
        }
        p += __shfl_xor(p, 16);             // reduce across the 4 lg groups
        p += __shfl_xor(p, 32);
        if (lg == 0) Ob[row] = p + bias3;
    }

    __syncthreads();   // Ob complete across waves

    // ---- cooperative out store: one float4 wave-store covers the block ----
    if (t < NTILE) {
        float4 o;
        o.x = Ob[0 * NTILE + t];
        o.y = Ob[1 * NTILE + t];
        o.z = Ob[2 * NTILE + t];
        o.w = Ob[3 * NTILE + t];
        *(float4*)&out[(size_t)(n0 + t) * AA + a0] = o;
    }
}

extern "C" void kernel_launch(void* const* d_in, const int* in_sizes, int n_in,
                              void* d_out, int out_size, void* d_ws, size_t ws_size,
                              hipStream_t stream) {
    const float* desc    = (const float*)d_in[0];
    const int*   numbers = (const int*)  d_in[1];
    const float* W1      = (const float*)d_in[2];
    const float* b1      = (const float*)d_in[3];
    const float* W2      = (const float*)d_in[4];
    const float* b2      = (const float*)d_in[5];
    const float* W3      = (const float*)d_in[6];
    const float* b3      = (const float*)d_in[7];
    float*       out     = (float*)d_out;

    unsigned short* Wf = (unsigned short*)d_ws;                  // 8*16384 B
    float*          Bp = (float*)((char*)d_ws + 8 * WFS * 2);    // 8*256 f32

    hipLaunchKernelGGL(prep_weights, dim3(64), dim3(256), 0, stream,
                       W1, b1, W2, b2, W3, b3, Wf, Bp);

    dim3 grid(AA / ATILE, NN / NTILE);
    hipLaunchKernelGGL(atomic_mlp_mfma, grid, dim3(256), 0, stream,
                       desc, numbers, Wf, Bp, out);
}